// Round 6
// baseline (776.177 us; speedup 1.0000x reference)
//
#include <hip/hip_runtime.h>

typedef __attribute__((ext_vector_type(8))) short short8;
typedef __attribute__((ext_vector_type(4))) float f32x4;

#define MFMA16(a, b, c) __builtin_amdgcn_mfma_f32_16x16x32_bf16((a), (b), (c), 0, 0, 0)

constexpr int Bv  = 32;    // batch
constexpr int Lv  = 168;   // encoder length
constexpr int Sv  = 512;   // sites
constexpr int HZv = 24;    // horizon
constexpr int Mv  = 64;    // sequences per block (256 blocks, 1 per CU)
constexpr int HSTR = 88;   // h-row stride (shorts)
constexpr int HBUF = Mv * HSTR;   // 5632 shorts per buffer
constexpr int WFR  = 512;         // shorts per MFMA B-fragment (64 lanes x 8)
constexpr int WMAT = 32 * WFR;    // 16384 shorts per 256x64 matrix

// gate prescale factors folded into weights/biases at pack time:
// i,f,o rows: -log2(e)  -> sigm(x) = rcp(1 + exp2(p)),  p = -log2e*x
// g row:     2*log2(e)  -> tanh(x) = 1 - 2*rcp(exp2(p)+1), p = 2log2e*x
__device__ __constant__ float GF[4] = {-1.44269504088896f, -1.44269504088896f,
                                        2.88539008177793f, -1.44269504088896f};

__device__ __forceinline__ float b2f(short s) {
    unsigned u = ((unsigned)(unsigned short)s) << 16;
    return __builtin_bit_cast(float, u);
}
__device__ __forceinline__ short f2b(float f) {
    unsigned u = __builtin_bit_cast(unsigned, f);
    unsigned r = (u + 0x7FFFu + ((u >> 16) & 1u)) >> 16;   // RNE
    return (short)(unsigned short)r;
}
// packed f32->bf16 RNE (1 instr for 2 values); no builtin on gfx950 -> asm
__device__ __forceinline__ unsigned pkbf16(float lo, float hi) {
    unsigned r;
    asm("v_cvt_pk_bf16_f32 %0, %1, %2" : "=v"(r) : "v"(lo), "v"(hi));
    return r;
}
// prescaled activations: input already multiplied by the gate factor
__device__ __forceinline__ float sigmP(float p) {            // p = -log2e*x
    float e = __builtin_amdgcn_exp2f(p);
    return __builtin_amdgcn_rcpf(1.0f + e);
}
__device__ __forceinline__ float tanhP(float p) {            // p = 2log2e*x
    float e = __builtin_amdgcn_exp2f(p);
    return 1.0f - 2.0f * __builtin_amdgcn_rcpf(e + 1.0f);
}
__device__ __forceinline__ float tanh_(float x) {            // unscaled (cell)
    float e = __builtin_amdgcn_exp2f(2.88539008177793f * x);
    return 1.0f - 2.0f * __builtin_amdgcn_rcpf(e + 1.0f);
}
__device__ __forceinline__ void hi8s(const float* __restrict__ p, float s, short8& hi) {
#pragma unroll
    for (int j = 0; j < 8; ++j) hi[j] = f2b(p[j] * s);
}

// r19: r18 + layer-1 weights (Wih1, Whh1: 16 frags = 64 VGPR) promoted from
// LDS-streamed to per-wave REGISTERS, loaded once from the packed LDS image.
// Rationale: 16 waves x 24 frag-reads x 1KiB = 384 KB/CU-step of invariant
// LDS traffic (~1536 cy at 256 B/cy) was ~21% of the step. Now only Whh0
// (8 frags) streams per step. VGPR 52 -> ~116 of the 128 cap a 1024-thread
// block enforces (16 waves x 128 = 2048-reg pool), so occupancy holds.
__global__ __launch_bounds__(1024)
void sitewise_lstm(const float* __restrict__ x_seq,
                   const float* __restrict__ Wih0, const float* __restrict__ Whh0,
                   const float* __restrict__ bih0, const float* __restrict__ bhh0,
                   const float* __restrict__ Wih1, const float* __restrict__ Whh1,
                   const float* __restrict__ bih1, const float* __restrict__ bhh1,
                   const float* __restrict__ Wcih, const float* __restrict__ Wchh,
                   const float* __restrict__ bcih, const float* __restrict__ bchh,
                   const float* __restrict__ Wout, const float* __restrict__ bout,
                   float* __restrict__ out)
{
    __shared__ __align__(16) short Wlds[3 * WMAT];   // 96 KB  [Whh0|Wih1|Whh1], slot0 -> Wchh in decoder
    __shared__ __align__(16) short Hhi[4 * HBUF];    // 45 KB  h double-buffers, 2 layers
    __shared__ float woutF[64];
    __shared__ float ybufF[Mv];

    const int tid  = threadIdx.x;
    const int wv   = tid >> 6;    // 0..15
    const int lane = tid & 63;
    const int q    = lane >> 4;
    const int col  = lane & 15;
    const int mh   = wv >> 2;     // m-quarter: m in [16mh, 16mh+16)
    const int U    = wv & 3;      // unit-slice: u in [16U, 16U+16)
    const int bid  = blockIdx.x;
    const int b    = bid >> 3;
    const int s0   = (bid & 7) << 6;
    const int uu   = U * 16 + col;
    const int me   = mh * 16 + q * 4;          // epilogue m base (+ r)

    const int roA  = (mh * 16 + col) * HSTR + q * 8;   // A-frag read (+ kc*32)
    const int wiA  = me * HSTR + uu;                   // h write (+ r*HSTR)
    const int wb0  = (U * 8) * WFR + lane * 8;         // mat0 frag base (+ (kc*4+g)*WFR)
    const int wb1  = WMAT + wb0;
    const int wb2  = 2 * WMAT + wb0;

    // ---- zero H buffers ----
    for (int i = tid; i < 4 * HBUF / 2; i += 1024) ((int*)Hhi)[i] = 0;
    if (tid < 64) woutF[tid] = Wout[tid];

    // ---- pack PRESCALED weights into LDS fragments: frag(mat, U,kc,g),
    //      lane l holds GF[g]*W[g*64+U*16+(l&15)][kc*32+(l>>4)*8 ..+8] bf16 ----
    for (int idx = tid; idx < 96 * 64; idx += 1024) {
        const int fid = idx >> 6;          // 0..95
        const int ln  = idx & 63;
        const int mat = fid >> 5;          // 0..2
        const int fm  = fid & 31;          // U*8 + kc*4 + g
        const int Uw  = fm >> 3;
        const int kc  = (fm >> 2) & 1;
        const int g   = fm & 3;
        const float* Wm = (mat == 0) ? Whh0 : (mat == 1) ? Wih1 : Whh1;
        const int j   = g * 64 + Uw * 16 + (ln & 15);
        const int cc  = kc * 32 + (ln >> 4) * 8;
        short8 hv; hi8s(Wm + j * 64 + cc, GF[g], hv);
        *(short8*)(Wlds + fid * WFR + ln * 8) = hv;
    }

    const float* xbF = x_seq + b * Lv * Sv + s0;

    // ---- per-lane scalars (prescaled) ----
    float bias0[4], bias1[4], wih0gE[4];
#pragma unroll
    for (int g = 0; g < 4; ++g) {
        const int j = g * 64 + uu;
        bias0[g]  = (bih0[j] + bhh0[j]) * GF[g];
        bias1[g]  = (bih1[j] + bhh1[j]) * GF[g];
        wih0gE[g] = Wih0[j] * GF[g];
    }

    float c0[4], c1[4];
#pragma unroll
    for (int i = 0; i < 4; ++i) { c0[i] = 0.f; c1[i] = 0.f; }

    __syncthreads();   // Hhi zeroed + Wlds packed visible

    // ---- layer-1 weights -> registers, once (64 VGPR; invariant all steps) ----
    short8 w1r[8], w2r[8];
#pragma unroll
    for (int f = 0; f < 8; ++f) {
        w1r[f] = *(const short8*)(Wlds + wb1 + f * WFR);
        w2r[f] = *(const short8*)(Wlds + wb2 + f * WFR);
    }

// one fused 2-layer encoder step, ONE barrier; buffer bases are literals
#define ENC_STEP(T, B0P, B0N, B1P, B1N) do {                                          \
        f32x4 xv = *(const f32x4*)(xbF + (T) * Sv + me);                              \
        short8 ah0 = *(const short8*)(Hhi + (B0P) + roA);                             \
        short8 ah1 = *(const short8*)(Hhi + (B0P) + roA + 32);                        \
        short8 wf[8];                                                                 \
        _Pragma("unroll")                                                             \
        for (int f = 0; f < 8; ++f) wf[f] = *(const short8*)(Wlds + wb0 + f * WFR);   \
        f32x4 pre0[4];                                                                \
        _Pragma("unroll")                                                             \
        for (int g = 0; g < 4; ++g)                                                   \
            pre0[g] = (f32x4){bias0[g], bias0[g], bias0[g], bias0[g]};                \
        _Pragma("unroll")                                                             \
        for (int g = 0; g < 4; ++g) pre0[g] = MFMA16(ah0, wf[g],     pre0[g]);        \
        _Pragma("unroll")                                                             \
        for (int g = 0; g < 4; ++g) pre0[g] = MFMA16(ah1, wf[4 + g], pre0[g]);        \
        float h0v[4];                                                                 \
        _Pragma("unroll")                                                             \
        for (int r = 0; r < 4; ++r) {                                                 \
            const float xw = xv[r];                                                   \
            const float ig = sigmP(pre0[0][r] + xw * wih0gE[0]);                      \
            const float fg = sigmP(pre0[1][r] + xw * wih0gE[1]);                      \
            const float gt = tanhP(pre0[2][r] + xw * wih0gE[2]);                      \
            const float og = sigmP(pre0[3][r] + xw * wih0gE[3]);                      \
            const float c  = fg * c0[r] + ig * gt;                                    \
            c0[r] = c;                                                                \
            h0v[r] = og * tanh_(c);                                                   \
        }                                                                             \
        {                                                                             \
            const unsigned p01 = pkbf16(h0v[0], h0v[1]);                              \
            const unsigned p23 = pkbf16(h0v[2], h0v[3]);                              \
            Hhi[(B0N) + wiA + 0 * HSTR] = (short)p01;                                 \
            Hhi[(B0N) + wiA + 1 * HSTR] = (short)(p01 >> 16);                         \
            Hhi[(B0N) + wiA + 2 * HSTR] = (short)p23;                                 \
            Hhi[(B0N) + wiA + 3 * HSTR] = (short)(p23 >> 16);                         \
        }                                                                             \
        __syncthreads();   /* the ONLY barrier: h0(new) visible */                    \
        short8 bh0 = *(const short8*)(Hhi + (B0N) + roA);                             \
        short8 bh1 = *(const short8*)(Hhi + (B0N) + roA + 32);                        \
        short8 dh0 = *(const short8*)(Hhi + (B1P) + roA);                             \
        short8 dh1 = *(const short8*)(Hhi + (B1P) + roA + 32);                        \
        f32x4 pre1[4];                                                                \
        _Pragma("unroll")                                                             \
        for (int g = 0; g < 4; ++g)                                                   \
            pre1[g] = (f32x4){bias1[g], bias1[g], bias1[g], bias1[g]};                \
        _Pragma("unroll")                                                             \
        for (int g = 0; g < 4; ++g) pre1[g] = MFMA16(bh0, w1r[g],     pre1[g]);       \
        _Pragma("unroll")                                                             \
        for (int g = 0; g < 4; ++g) pre1[g] = MFMA16(bh1, w1r[4 + g], pre1[g]);       \
        _Pragma("unroll")                                                             \
        for (int g = 0; g < 4; ++g) pre1[g] = MFMA16(dh0, w2r[g],     pre1[g]);       \
        _Pragma("unroll")                                                             \
        for (int g = 0; g < 4; ++g) pre1[g] = MFMA16(dh1, w2r[4 + g], pre1[g]);       \
        float h1v[4];                                                                 \
        _Pragma("unroll")                                                             \
        for (int r = 0; r < 4; ++r) {                                                 \
            const float ig = sigmP(pre1[0][r]);                                       \
            const float fg = sigmP(pre1[1][r]);                                       \
            const float gt = tanhP(pre1[2][r]);                                       \
            const float og = sigmP(pre1[3][r]);                                       \
            const float c  = fg * c1[r] + ig * gt;                                    \
            c1[r] = c;                                                                \
            h1v[r] = og * tanh_(c);                                                   \
        }                                                                             \
        {                                                                             \
            const unsigned p01 = pkbf16(h1v[0], h1v[1]);                              \
            const unsigned p23 = pkbf16(h1v[2], h1v[3]);                              \
            Hhi[(B1N) + wiA + 0 * HSTR] = (short)p01;                                 \
            Hhi[(B1N) + wiA + 1 * HSTR] = (short)(p01 >> 16);                         \
            Hhi[(B1N) + wiA + 2 * HSTR] = (short)p23;                                 \
            Hhi[(B1N) + wiA + 3 * HSTR] = (short)(p23 >> 16);                         \
        }                                                                             \
        /* no barrier 2: h1new visibility is provided by next step's barrier,  */     \
        /* which sits before the only B1n reader (next phase 2b)               */     \
    } while (0)

    for (int t = 0; t < Lv; t += 2) {
        ENC_STEP(t,     0 * HBUF, 1 * HBUF, 2 * HBUF, 3 * HBUF);
        ENC_STEP(t + 1, 1 * HBUF, 0 * HBUF, 3 * HBUF, 2 * HBUF);
    }
#undef ENC_STEP

    // ================= decoder =================
    // repack mat0 slot <- Wchh prescaled (last mat0 read was final phase1)
    for (int idx = tid; idx < 32 * 64; idx += 1024) {
        const int fid = idx >> 6;          // 0..31
        const int ln  = idx & 63;
        const int Uw  = fid >> 3;
        const int kc  = (fid >> 2) & 1;
        const int g   = fid & 3;
        const int j   = g * 64 + Uw * 16 + (ln & 15);
        const int cc  = kc * 32 + (ln >> 4) * 8;
        short8 hv; hi8s(Wchh + j * 64 + cc, GF[g], hv);
        *(short8*)(Wlds + fid * WFR + ln * 8) = hv;
    }
    float biasc[4], wcihgE[4];
#pragma unroll
    for (int g = 0; g < 4; ++g) {
        const int j = g * 64 + uu;
        biasc[g]  = (bcih[j] + bchh[j]) * GF[g];
        wcihgE[g] = Wcih[j] * GF[g];
    }
    if (tid < Mv) ybufF[tid] = xbF[(Lv - 1) * Sv + tid];
    __syncthreads();   // h1(final, buf 2) + Wchh pack + ybufF visible

    const float boutF = bout[0];
    float* outp = out + b * HZv * Sv + s0;

#define DEC_STEP(T, B1P, B1N) do {                                                    \
        short8 ah0 = *(const short8*)(Hhi + (B1P) + roA);                             \
        short8 ah1 = *(const short8*)(Hhi + (B1P) + roA + 32);                        \
        short8 wf[8];                                                                 \
        _Pragma("unroll")                                                             \
        for (int f = 0; f < 8; ++f) wf[f] = *(const short8*)(Wlds + wb0 + f * WFR);   \
        float yv[4];                                                                  \
        _Pragma("unroll")                                                             \
        for (int r = 0; r < 4; ++r)                                                   \
            yv[r] = ybufF[me + r];                                                    \
        f32x4 prc[4];                                                                 \
        _Pragma("unroll")                                                             \
        for (int g = 0; g < 4; ++g)                                                   \
            prc[g] = (f32x4){biasc[g], biasc[g], biasc[g], biasc[g]};                 \
        _Pragma("unroll")                                                             \
        for (int g = 0; g < 4; ++g) prc[g] = MFMA16(ah0, wf[g],     prc[g]);          \
        _Pragma("unroll")                                                             \
        for (int g = 0; g < 4; ++g) prc[g] = MFMA16(ah1, wf[4 + g], prc[g]);          \
        float hdv[4];                                                                 \
        _Pragma("unroll")                                                             \
        for (int r = 0; r < 4; ++r) {                                                 \
            const float xw = yv[r];                                                   \
            const float ig = sigmP(prc[0][r] + xw * wcihgE[0]);                       \
            const float fg = sigmP(prc[1][r] + xw * wcihgE[1]);                       \
            const float gt = tanhP(prc[2][r] + xw * wcihgE[2]);                       \
            const float og = sigmP(prc[3][r] + xw * wcihgE[3]);                       \
            const float c  = fg * c1[r] + ig * gt;                                    \
            c1[r] = c;                                                                \
            hdv[r] = og * tanh_(c);                                                   \
        }                                                                             \
        {                                                                             \
            const unsigned p01 = pkbf16(hdv[0], hdv[1]);                              \
            const unsigned p23 = pkbf16(hdv[2], hdv[3]);                              \
            Hhi[(B1N) + wiA + 0 * HSTR] = (short)p01;                                 \
            Hhi[(B1N) + wiA + 1 * HSTR] = (short)(p01 >> 16);                         \
            Hhi[(B1N) + wiA + 2 * HSTR] = (short)p23;                                 \
            Hhi[(B1N) + wiA + 3 * HSTR] = (short)(p23 >> 16);                         \
        }                                                                             \
        __syncthreads();   /* h(new) visible for y projection */                      \
        {                  /* all 1024 threads: 16 lanes per m, 4 k each */           \
            const int m  = tid >> 4;                                                  \
            const int pp = tid & 15;                                                  \
            float s = 0.f;                                                            \
            _Pragma("unroll")                                                         \
            for (int k = 0; k < 4; ++k)                                               \
                s += b2f(Hhi[(B1N) + m * HSTR + pp * 4 + k]) * woutF[pp * 4 + k];     \
            s += __shfl_xor(s, 1, 64);                                                \
            s += __shfl_xor(s, 2, 64);                                                \
            s += __shfl_xor(s, 4, 64);                                                \
            s += __shfl_xor(s, 8, 64);                                                \
            if (pp == 0) {                                                            \
                const float y = s + boutF;                                            \
                outp[(T) * Sv + m] = y;                                               \
                ybufF[m] = y;                                                         \
            }                                                                         \
        }                                                                             \
        __syncthreads();   /* ybufF visible for next step */                          \
    } while (0)

    for (int t = 0; t < HZv; t += 2) {
        DEC_STEP(t,     2 * HBUF, 3 * HBUF);
        DEC_STEP(t + 1, 3 * HBUF, 2 * HBUF);
    }
#undef DEC_STEP
}

extern "C" void kernel_launch(void* const* d_in, const int* in_sizes, int n_in,
                              void* d_out, int out_size, void* d_ws, size_t ws_size,
                              hipStream_t stream)
{
    const float* x_seq = (const float*)d_in[0];
    const float* Wih0  = (const float*)d_in[1];
    const float* Whh0  = (const float*)d_in[2];
    const float* bih0  = (const float*)d_in[3];
    const float* bhh0  = (const float*)d_in[4];
    const float* Wih1  = (const float*)d_in[5];
    const float* Whh1  = (const float*)d_in[6];
    const float* bih1  = (const float*)d_in[7];
    const float* bhh1  = (const float*)d_in[8];
    const float* Wcih  = (const float*)d_in[9];
    const float* Wchh  = (const float*)d_in[10];
    const float* bcih  = (const float*)d_in[11];
    const float* bchh  = (const float*)d_in[12];
    const float* Wout  = (const float*)d_in[13];
    const float* bout  = (const float*)d_in[14];
    float* out = (float*)d_out;

    hipLaunchKernelGGL(sitewise_lstm, dim3(Bv * (Sv / Mv)), dim3(1024), 0, stream,
                       x_seq, Wih0, Whh0, bih0, bhh0, Wih1, Whh1, bih1, bhh1,
                       Wcih, Wchh, bcih, bchh, Wout, bout, out);
}

// Round 7
// 465.945 us; speedup vs baseline: 1.6658x; 1.6658x over previous
//
#include <hip/hip_runtime.h>

typedef __attribute__((ext_vector_type(8))) short short8;
typedef __attribute__((ext_vector_type(4))) float f32x4;

#define MFMA16(a, b, c) __builtin_amdgcn_mfma_f32_16x16x32_bf16((a), (b), (c), 0, 0, 0)

constexpr int Bv  = 32;    // batch
constexpr int Lv  = 168;   // encoder length
constexpr int Sv  = 512;   // sites
constexpr int HZv = 24;    // horizon
constexpr int Mv  = 64;    // sequences per block (256 blocks, 1 per CU)
constexpr int HSTR = 88;   // h-row stride (shorts)
constexpr int HBUF = Mv * HSTR;   // 5632 shorts; slots: 0,1 = h0 dbuf; 2,3 = h1 dbuf
constexpr int WFR  = 512;         // shorts per MFMA B-fragment (64 lanes x 8)

// gate prescale factors folded into weights/biases at pack time:
// i,f,o rows: -log2(e)  -> sigm(x) = rcp(1 + exp2(p)),  p = -log2e*x
// g row:     2*log2(e)  -> tanh(x) = 1 - 2*rcp(exp2(p)+1), p = 2log2e*x
__device__ __constant__ float GF[4] = {-1.44269504088896f, -1.44269504088896f,
                                        2.88539008177793f, -1.44269504088896f};

__device__ __forceinline__ float b2f(short s) {
    unsigned u = ((unsigned)(unsigned short)s) << 16;
    return __builtin_bit_cast(float, u);
}
__device__ __forceinline__ short f2b(float f) {
    unsigned u = __builtin_bit_cast(unsigned, f);
    unsigned r = (u + 0x7FFFu + ((u >> 16) & 1u)) >> 16;   // RNE
    return (short)(unsigned short)r;
}
__device__ __forceinline__ unsigned pkbf16(float lo, float hi) {
    unsigned r;
    asm("v_cvt_pk_bf16_f32 %0, %1, %2" : "=v"(r) : "v"(lo), "v"(hi));
    return r;
}
__device__ __forceinline__ float sigmP(float p) {            // p = -log2e*x
    float e = __builtin_amdgcn_exp2f(p);
    return __builtin_amdgcn_rcpf(1.0f + e);
}
__device__ __forceinline__ float tanhP(float p) {            // p = 2log2e*x
    float e = __builtin_amdgcn_exp2f(p);
    return 1.0f - 2.0f * __builtin_amdgcn_rcpf(e + 1.0f);
}
__device__ __forceinline__ float tanh_(float x) {            // unscaled (cell)
    float e = __builtin_amdgcn_exp2f(2.88539008177793f * x);
    return 1.0f - 2.0f * __builtin_amdgcn_rcpf(e + 1.0f);
}
__device__ __forceinline__ void hi8s(const float* __restrict__ p, float s, short8& hi) {
#pragma unroll
    for (int j = 0; j < 8; ++j) hi[j] = f2b(p[j] * s);
}

// r20: layer-pipelined wave specialization. Waves 0-7 = layer0 (step t+1),
// waves 8-15 = layer1 (step t), each wave a 32m x 16u tile (mt=2), ONE
// barrier per interval in UNIFORM control flow. Register law respected:
// L0 regs = Whh0 frags (32), L1 regs = Wih1 frags (32) + Whh1 streamed
// one-frag-at-a-time from 32KB LDS -> peak ~100 VGPR (no spill; r16/r19
// died from promotion+streaming coexisting under the 128 cap).
__global__ __launch_bounds__(1024)
void sitewise_lstm(const float* __restrict__ x_seq,
                   const float* __restrict__ Wih0, const float* __restrict__ Whh0,
                   const float* __restrict__ bih0, const float* __restrict__ bhh0,
                   const float* __restrict__ Wih1, const float* __restrict__ Whh1,
                   const float* __restrict__ bih1, const float* __restrict__ bhh1,
                   const float* __restrict__ Wcih, const float* __restrict__ Wchh,
                   const float* __restrict__ bcih, const float* __restrict__ bchh,
                   const float* __restrict__ Wout, const float* __restrict__ bout,
                   float* __restrict__ out)
{
    __shared__ __align__(16) short Wlds[32 * WFR];   // 32 KB: Whh1 frags
    __shared__ __align__(16) short Hhi[4 * HBUF];    // 45 KB: h0 dbuf, h1 dbuf
    __shared__ float woutF[64];
    __shared__ float ybufF[Mv];

    const int tid  = threadIdx.x;
    const int wv   = tid >> 6;        // 0..15
    const int lane = tid & 63;
    const int q    = lane >> 4;
    const int col  = lane & 15;
    const bool isL0 = (wv < 8);
    const int wq   = wv & 7;
    const int mh   = wq >> 2;         // 0..1: m in [32mh, 32mh+32)
    const int U    = wq & 3;          // u in [16U, 16U+16)
    const int bid  = blockIdx.x;
    const int b    = bid >> 3;
    const int s0   = (bid & 7) << 6;
    const int uu   = U * 16 + col;
    const int me   = mh * 32 + q * 4;                  // epilogue m base (+ mt*16 + r)

    const int roA  = (mh * 32 + col) * HSTR + q * 8;   // A-frag read (+ mt*16*HSTR, +32 for kc1)
    const int wiA  = me * HSTR + uu;                   // h write (+ (mt*16+r)*HSTR)
    const int wb   = (U * 8) * WFR + lane * 8;         // Wlds frag base (+ (kc*4+g)*WFR)

    // ---- zero H buffers; wout ----
    for (int i = tid; i < 4 * HBUF / 2; i += 1024) ((int*)Hhi)[i] = 0;
    if (tid < 64) woutF[tid] = Wout[tid];

    // ---- pack PRESCALED Whh1 into LDS fragments ----
    for (int idx = tid; idx < 32 * 64; idx += 1024) {
        const int fid = idx >> 6;      // Uw*8 + kc*4 + g
        const int ln  = idx & 63;
        const int Uw  = fid >> 3;
        const int kc  = (fid >> 2) & 1;
        const int g   = fid & 3;
        const int j   = g * 64 + Uw * 16 + (ln & 15);
        const int cc  = kc * 32 + (ln >> 4) * 8;
        short8 hv; hi8s(Whh1 + j * 64 + cc, GF[g], hv);
        *(short8*)(Wlds + fid * WFR + ln * 8) = hv;
    }

    const float* xbF = x_seq + b * Lv * Sv + s0;

    // ---- per-wave-role scalars + register weight matrix ----
    float ba[4], we[4];
    short8 wreg[8];      // L0: Whh0 frags; L1: Wih1 frags; decoder: Wchh frags
    const float* WmA = isL0 ? Whh0 : Wih1;
#pragma unroll
    for (int g = 0; g < 4; ++g) {
        const int j = g * 64 + uu;
        ba[g] = (isL0 ? (bih0[j] + bhh0[j]) : (bih1[j] + bhh1[j])) * GF[g];
        we[g] = Wih0[j] * GF[g];       // used by L0 only in encoder
#pragma unroll
        for (int kc = 0; kc < 2; ++kc)
            hi8s(WmA + j * 64 + kc * 32 + q * 8, GF[g], wreg[kc * 4 + g]);
    }

    float cs[8];         // c-state: L0 waves hold c0, L1 waves hold c1
#pragma unroll
    for (int i = 0; i < 8; ++i) cs[i] = 0.f;

    __syncthreads();   // Hhi zeroed + Wlds packed visible

// layer-0 step T: read h0 slot RP (0/1), write h0 slot WP
#define L0BODY(T, RP, WP) do {                                                        \
        _Pragma("unroll")                                                             \
        for (int mt = 0; mt < 2; ++mt) {                                              \
            const f32x4 xv = *(const f32x4*)(xbF + (T) * Sv + me + mt * 16);          \
            const short8 a0 = *(const short8*)(Hhi + (RP) * HBUF + roA + mt * 16 * HSTR);      \
            const short8 a1 = *(const short8*)(Hhi + (RP) * HBUF + roA + mt * 16 * HSTR + 32); \
            f32x4 pre[4];                                                             \
            _Pragma("unroll")                                                         \
            for (int g = 0; g < 4; ++g) pre[g] = (f32x4){ba[g], ba[g], ba[g], ba[g]}; \
            _Pragma("unroll")                                                         \
            for (int g = 0; g < 4; ++g) pre[g] = MFMA16(a0, wreg[g],     pre[g]);     \
            _Pragma("unroll")                                                         \
            for (int g = 0; g < 4; ++g) pre[g] = MFMA16(a1, wreg[4 + g], pre[g]);     \
            float hv[4];                                                              \
            _Pragma("unroll")                                                         \
            for (int r = 0; r < 4; ++r) {                                             \
                const float xw = xv[r];                                               \
                const float ig = sigmP(pre[0][r] + xw * we[0]);                       \
                const float fg = sigmP(pre[1][r] + xw * we[1]);                       \
                const float gt = tanhP(pre[2][r] + xw * we[2]);                       \
                const float og = sigmP(pre[3][r] + xw * we[3]);                       \
                const float c  = fg * cs[mt * 4 + r] + ig * gt;                       \
                cs[mt * 4 + r] = c;                                                   \
                hv[r] = og * tanh_(c);                                                \
            }                                                                         \
            const unsigned p01 = pkbf16(hv[0], hv[1]);                                \
            const unsigned p23 = pkbf16(hv[2], hv[3]);                                \
            Hhi[(WP) * HBUF + wiA + (mt * 16 + 0) * HSTR] = (short)p01;               \
            Hhi[(WP) * HBUF + wiA + (mt * 16 + 1) * HSTR] = (short)(p01 >> 16);       \
            Hhi[(WP) * HBUF + wiA + (mt * 16 + 2) * HSTR] = (short)p23;               \
            Hhi[(WP) * HBUF + wiA + (mt * 16 + 3) * HSTR] = (short)(p23 >> 16);       \
        }                                                                             \
    } while (0)

// layer-1 step: read h0 slot RP0 (0/1), h1 slot RPH (2/3), write h1 slot WPH
#define L1BODY(RP0, RPH, WPH) do {                                                    \
        _Pragma("unroll")                                                             \
        for (int mt = 0; mt < 2; ++mt) {                                              \
            const short8 b0 = *(const short8*)(Hhi + (RP0) * HBUF + roA + mt * 16 * HSTR);      \
            const short8 b1 = *(const short8*)(Hhi + (RP0) * HBUF + roA + mt * 16 * HSTR + 32); \
            const short8 d0 = *(const short8*)(Hhi + (RPH) * HBUF + roA + mt * 16 * HSTR);      \
            const short8 d1 = *(const short8*)(Hhi + (RPH) * HBUF + roA + mt * 16 * HSTR + 32); \
            f32x4 pre[4];                                                             \
            _Pragma("unroll")                                                         \
            for (int g = 0; g < 4; ++g) pre[g] = (f32x4){ba[g], ba[g], ba[g], ba[g]}; \
            _Pragma("unroll")                                                         \
            for (int g = 0; g < 4; ++g) pre[g] = MFMA16(b0, wreg[g],     pre[g]);     \
            _Pragma("unroll")                                                         \
            for (int g = 0; g < 4; ++g) pre[g] = MFMA16(b1, wreg[4 + g], pre[g]);     \
            _Pragma("unroll")                                                         \
            for (int g = 0; g < 4; ++g) {                                             \
                const short8 wf = *(const short8*)(Wlds + wb + g * WFR);              \
                pre[g] = MFMA16(d0, wf, pre[g]);                                      \
            }                                                                         \
            _Pragma("unroll")                                                         \
            for (int g = 0; g < 4; ++g) {                                             \
                const short8 wf = *(const short8*)(Wlds + wb + (4 + g) * WFR);        \
                pre[g] = MFMA16(d1, wf, pre[g]);                                      \
            }                                                                         \
            float hv[4];                                                              \
            _Pragma("unroll")                                                         \
            for (int r = 0; r < 4; ++r) {                                             \
                const float ig = sigmP(pre[0][r]);                                    \
                const float fg = sigmP(pre[1][r]);                                    \
                const float gt = tanhP(pre[2][r]);                                    \
                const float og = sigmP(pre[3][r]);                                    \
                const float c  = fg * cs[mt * 4 + r] + ig * gt;                       \
                cs[mt * 4 + r] = c;                                                   \
                hv[r] = og * tanh_(c);                                                \
            }                                                                         \
            const unsigned p01 = pkbf16(hv[0], hv[1]);                                \
            const unsigned p23 = pkbf16(hv[2], hv[3]);                                \
            Hhi[(WPH) * HBUF + wiA + (mt * 16 + 0) * HSTR] = (short)p01;              \
            Hhi[(WPH) * HBUF + wiA + (mt * 16 + 1) * HSTR] = (short)(p01 >> 16);      \
            Hhi[(WPH) * HBUF + wiA + (mt * 16 + 2) * HSTR] = (short)p23;              \
            Hhi[(WPH) * HBUF + wiA + (mt * 16 + 3) * HSTR] = (short)(p23 >> 16);      \
        }                                                                             \
    } while (0)

    // ---- encoder: 169 barrier intervals; interval k runs L0(k) || L1(k-1) ----
    // h0(t) -> slot t&1; h1(t) -> slot 2+(t&1). Slots 1,3 start zeroed (= t=-1).
    if (isL0) L0BODY(0, 1, 0);
    __syncthreads();
    for (int k = 1; k < 167; k += 2) {
        // odd interval k: L0(k): rd h0[0] wr h0[1]; L1(k-1): rd h0[0],h1[3] wr h1[2]
        if (isL0) L0BODY(k, 0, 1); else L1BODY(0, 3, 2);
        __syncthreads();
        // even interval k+1: L0: rd h0[1] wr h0[0]; L1(k): rd h0[1],h1[2] wr h1[3]
        if (isL0) L0BODY(k + 1, 1, 0); else L1BODY(1, 2, 3);
        __syncthreads();
    }
    if (isL0) L0BODY(167, 0, 1); else L1BODY(0, 3, 2);   // interval 167 (odd)
    __syncthreads();
    if (!isL0) L1BODY(1, 2, 3);                          // interval 168: L1(167) only
    __syncthreads();
    // h1(167) now in slot 3; c1 state lives in L1 waves' cs[8]

    // ================= decoder (runs on L1 waves; projection on all) =================
#pragma unroll
    for (int g = 0; g < 4; ++g) {
        const int j = g * 64 + uu;
        ba[g] = (bcih[j] + bchh[j]) * GF[g];
        we[g] = Wcih[j] * GF[g];
#pragma unroll
        for (int kc = 0; kc < 2; ++kc)
            hi8s(Wchh + j * 64 + kc * 32 + q * 8, GF[g], wreg[kc * 4 + g]);
    }
    if (tid < Mv) ybufF[tid] = xbF[(Lv - 1) * Sv + tid];
    __syncthreads();   // ybufF visible (h1 slot 3 already visible)

    const float boutF = bout[0];
    float* outp = out + b * HZv * Sv + s0;

#define DECBODY(T, RPH, WPH) do {                                                     \
        if (!isL0) {                                                                  \
            _Pragma("unroll")                                                         \
            for (int mt = 0; mt < 2; ++mt) {                                          \
                const f32x4 yv = *(const f32x4*)(ybufF + me + mt * 16);               \
                const short8 a0 = *(const short8*)(Hhi + (RPH) * HBUF + roA + mt * 16 * HSTR);      \
                const short8 a1 = *(const short8*)(Hhi + (RPH) * HBUF + roA + mt * 16 * HSTR + 32); \
                f32x4 pre[4];                                                         \
                _Pragma("unroll")                                                     \
                for (int g = 0; g < 4; ++g) pre[g] = (f32x4){ba[g], ba[g], ba[g], ba[g]}; \
                _Pragma("unroll")                                                     \
                for (int g = 0; g < 4; ++g) pre[g] = MFMA16(a0, wreg[g],     pre[g]); \
                _Pragma("unroll")                                                     \
                for (int g = 0; g < 4; ++g) pre[g] = MFMA16(a1, wreg[4 + g], pre[g]); \
                float hv[4];                                                          \
                _Pragma("unroll")                                                     \
                for (int r = 0; r < 4; ++r) {                                         \
                    const float xw = yv[r];                                           \
                    const float ig = sigmP(pre[0][r] + xw * we[0]);                   \
                    const float fg = sigmP(pre[1][r] + xw * we[1]);                   \
                    const float gt = tanhP(pre[2][r] + xw * we[2]);                   \
                    const float og = sigmP(pre[3][r] + xw * we[3]);                   \
                    const float c  = fg * cs[mt * 4 + r] + ig * gt;                   \
                    cs[mt * 4 + r] = c;                                               \
                    hv[r] = og * tanh_(c);                                            \
                }                                                                     \
                const unsigned p01 = pkbf16(hv[0], hv[1]);                            \
                const unsigned p23 = pkbf16(hv[2], hv[3]);                            \
                Hhi[(WPH) * HBUF + wiA + (mt * 16 + 0) * HSTR] = (short)p01;          \
                Hhi[(WPH) * HBUF + wiA + (mt * 16 + 1) * HSTR] = (short)(p01 >> 16);  \
                Hhi[(WPH) * HBUF + wiA + (mt * 16 + 2) * HSTR] = (short)p23;          \
                Hhi[(WPH) * HBUF + wiA + (mt * 16 + 3) * HSTR] = (short)(p23 >> 16);  \
            }                                                                         \
        }                                                                             \
        __syncthreads();   /* h(new) visible for y projection */                      \
        {                  /* all 1024 threads: 16 lanes per m, 4 k each */           \
            const int m  = tid >> 4;                                                  \
            const int pp = tid & 15;                                                  \
            float s = 0.f;                                                            \
            _Pragma("unroll")                                                         \
            for (int k2 = 0; k2 < 4; ++k2)                                            \
                s += b2f(Hhi[(WPH) * HBUF + m * HSTR + pp * 4 + k2]) * woutF[pp * 4 + k2]; \
            s += __shfl_xor(s, 1, 64);                                                \
            s += __shfl_xor(s, 2, 64);                                                \
            s += __shfl_xor(s, 4, 64);                                                \
            s += __shfl_xor(s, 8, 64);                                                \
            if (pp == 0) {                                                            \
                const float y = s + boutF;                                            \
                outp[(T) * Sv + m] = y;                                               \
                ybufF[m] = y;                                                         \
            }                                                                         \
        }                                                                             \
        __syncthreads();   /* ybufF visible for next step */                          \
    } while (0)

    for (int t = 0; t < HZv; t += 2) {
        DECBODY(t,     3, 2);
        DECBODY(t + 1, 2, 3);
    }
#undef DECBODY
#undef L1BODY
#undef L0BODY
}

extern "C" void kernel_launch(void* const* d_in, const int* in_sizes, int n_in,
                              void* d_out, int out_size, void* d_ws, size_t ws_size,
                              hipStream_t stream)
{
    const float* x_seq = (const float*)d_in[0];
    const float* Wih0  = (const float*)d_in[1];
    const float* Whh0  = (const float*)d_in[2];
    const float* bih0  = (const float*)d_in[3];
    const float* bhh0  = (const float*)d_in[4];
    const float* Wih1  = (const float*)d_in[5];
    const float* Whh1  = (const float*)d_in[6];
    const float* bih1  = (const float*)d_in[7];
    const float* bhh1  = (const float*)d_in[8];
    const float* Wcih  = (const float*)d_in[9];
    const float* Wchh  = (const float*)d_in[10];
    const float* bcih  = (const float*)d_in[11];
    const float* bchh  = (const float*)d_in[12];
    const float* Wout  = (const float*)d_in[13];
    const float* bout  = (const float*)d_in[14];
    float* out = (float*)d_out;

    hipLaunchKernelGGL(sitewise_lstm, dim3(Bv * (Sv / Mv)), dim3(1024), 0, stream,
                       x_seq, Wih0, Whh0, bih0, bhh0, Wih1, Whh1, bih1, bhh1,
                       Wcih, Wchh, bcih, bchh, Wout, bout, out);
}

// Round 9
// 458.527 us; speedup vs baseline: 1.6928x; 1.0162x over previous
//
#include <hip/hip_runtime.h>

typedef __attribute__((ext_vector_type(8))) short short8;
typedef __attribute__((ext_vector_type(4))) float f32x4;

#define MFMA16(a, b, c) __builtin_amdgcn_mfma_f32_16x16x32_bf16((a), (b), (c), 0, 0, 0)

constexpr int Bv  = 32;    // batch
constexpr int Lv  = 168;   // encoder length
constexpr int Sv  = 512;   // sites
constexpr int HZv = 24;    // horizon
constexpr int Mv  = 64;    // sequences per block (256 blocks, 1 per CU)
constexpr int HSTR = 88;   // h-row stride (shorts)
constexpr int HBUF = Mv * HSTR;   // 5632 shorts; slots: 0,1 = h0 dbuf; 2,3 = h1 dbuf
constexpr int WFR  = 512;         // shorts per MFMA B-fragment (64 lanes x 8)

// gate prescale factors folded into weights/biases at pack time:
// i,f,o rows: -log2(e)  -> sigm(x) = rcp(1 + exp2(p)),  p = -log2e*x
// g row:     2*log2(e)  -> tanh(x) = (exp2(p)-1)/(exp2(p)+1), p = 2log2e*x
__device__ __constant__ float GF[4] = {-1.44269504088896f, -1.44269504088896f,
                                        2.88539008177793f, -1.44269504088896f};

__device__ __forceinline__ float b2f(short s) {
    unsigned u = ((unsigned)(unsigned short)s) << 16;
    return __builtin_bit_cast(float, u);
}
__device__ __forceinline__ short f2b(float f) {
    unsigned u = __builtin_bit_cast(unsigned, f);
    unsigned r = (u + 0x7FFFu + ((u >> 16) & 1u)) >> 16;   // RNE
    return (short)(unsigned short)r;
}
__device__ __forceinline__ unsigned pkbf16(float lo, float hi) {
    unsigned r;
    asm("v_cvt_pk_bf16_f32 %0, %1, %2" : "=v"(r) : "v"(lo), "v"(hi));
    return r;
}

// LSTM cell epilogue, shared-rcp form, SCALAR (r21's packed-asm version NaN'd;
// this bisects: same math, compiler-emitted code).
//   sig(i)*tanh(g) = (e_g-1)*rcp(d_i*d_g);  sig(o)*tanh(c) = (e_c-1)*rcp(d_o*d_c)
// 5 exp2 + 3 rcp per element (was 5+5). Bounds audit: prescaled preacts
// |p| <= ~50 (weights/biases bf16-bounded) so e_* finite; pc clamped at 88
// so e_c <= 2^88; all denominators >= 1; max product ~2^112 < f32 max.
__device__ __forceinline__ float cell1(float pi, float pf, float pg, float po,
                                       float& c) {
    const float ei = __builtin_amdgcn_exp2f(pi);
    const float ef = __builtin_amdgcn_exp2f(pf);
    const float eg = __builtin_amdgcn_exp2f(pg);
    const float eo = __builtin_amdgcn_exp2f(po);
    const float rig = __builtin_amdgcn_rcpf((1.0f + ei) * (1.0f + eg));
    const float rf  = __builtin_amdgcn_rcpf(1.0f + ef);
    c = rf * c + (eg - 1.0f) * rig;
    const float pc = fminf(c * 2.88539008177793f, 88.0f);
    const float ec = __builtin_amdgcn_exp2f(pc);
    const float roc = __builtin_amdgcn_rcpf((1.0f + eo) * (1.0f + ec));
    return (ec - 1.0f) * roc;
}

__device__ __forceinline__ void hi8s(const float* __restrict__ p, float s, short8& hi) {
#pragma unroll
    for (int j = 0; j < 8; ++j) hi[j] = f2b(p[j] * s);
}

// r22: r20 pipeline (L0 waves 0-7 @ step t+1, L1 waves 8-15 @ step t, one
// barrier/interval, uniform flow) + shared-rcp epilogue in PLAIN SCALAR HIP
// (bisect of r21's NaN: keeps the 10->8 trans cut, drops all VOP3P asm).
__global__ __launch_bounds__(1024)
void sitewise_lstm(const float* __restrict__ x_seq,
                   const float* __restrict__ Wih0, const float* __restrict__ Whh0,
                   const float* __restrict__ bih0, const float* __restrict__ bhh0,
                   const float* __restrict__ Wih1, const float* __restrict__ Whh1,
                   const float* __restrict__ bih1, const float* __restrict__ bhh1,
                   const float* __restrict__ Wcih, const float* __restrict__ Wchh,
                   const float* __restrict__ bcih, const float* __restrict__ bchh,
                   const float* __restrict__ Wout, const float* __restrict__ bout,
                   float* __restrict__ out)
{
    __shared__ __align__(16) short Wlds[32 * WFR];   // 32 KB: Whh1 frags
    __shared__ __align__(16) short Hhi[4 * HBUF];    // 45 KB: h0 dbuf, h1 dbuf
    __shared__ __align__(16) float woutF[64];
    __shared__ __align__(16) float ybufF[Mv];

    const int tid  = threadIdx.x;
    const int wv   = tid >> 6;        // 0..15
    const int lane = tid & 63;
    const int q    = lane >> 4;
    const int col  = lane & 15;
    const bool isL0 = (wv < 8);
    const int wq   = wv & 7;
    const int mh   = wq >> 2;         // 0..1: m in [32mh, 32mh+32)
    const int U    = wq & 3;          // u in [16U, 16U+16)
    const int bid  = blockIdx.x;
    const int b    = bid >> 3;
    const int s0   = (bid & 7) << 6;
    const int uu   = U * 16 + col;
    const int me   = mh * 32 + q * 4;                  // epilogue m base (+ mt*16 + r)

    const int roA  = (mh * 32 + col) * HSTR + q * 8;   // A-frag read (+ mt*16*HSTR, +32 for kc1)
    const int wiA  = me * HSTR + uu;                   // h write (+ (mt*16+r)*HSTR)
    const int wb   = (U * 8) * WFR + lane * 8;         // Wlds frag base (+ (kc*4+g)*WFR)

    // ---- zero H buffers; wout ----
    for (int i = tid; i < 4 * HBUF / 2; i += 1024) ((int*)Hhi)[i] = 0;
    if (tid < 64) woutF[tid] = Wout[tid];

    // ---- pack PRESCALED Whh1 into LDS fragments ----
    for (int idx = tid; idx < 32 * 64; idx += 1024) {
        const int fid = idx >> 6;      // Uw*8 + kc*4 + g
        const int ln  = idx & 63;
        const int Uw  = fid >> 3;
        const int kc  = (fid >> 2) & 1;
        const int g   = fid & 3;
        const int j   = g * 64 + Uw * 16 + (ln & 15);
        const int cc  = kc * 32 + (ln >> 4) * 8;
        short8 hv; hi8s(Whh1 + j * 64 + cc, GF[g], hv);
        *(short8*)(Wlds + fid * WFR + ln * 8) = hv;
    }

    const float* xbF = x_seq + b * Lv * Sv + s0;

    // ---- per-wave-role scalars + register weight matrix ----
    float ba[4], we[4];
    short8 wreg[8];      // L0: Whh0 frags; L1: Wih1 frags; decoder: Wchh frags
    const float* WmA = isL0 ? Whh0 : Wih1;
#pragma unroll
    for (int g = 0; g < 4; ++g) {
        const int j = g * 64 + uu;
        ba[g] = (isL0 ? (bih0[j] + bhh0[j]) : (bih1[j] + bhh1[j])) * GF[g];
        we[g] = Wih0[j] * GF[g];       // used by L0 only in encoder
#pragma unroll
        for (int kc = 0; kc < 2; ++kc)
            hi8s(WmA + j * 64 + kc * 32 + q * 8, GF[g], wreg[kc * 4 + g]);
    }

    float cs[8];         // c-state: L0 waves hold c0, L1 waves hold c1
#pragma unroll
    for (int i = 0; i < 8; ++i) cs[i] = 0.f;

    __syncthreads();   // Hhi zeroed + Wlds packed visible

// layer-0 step T: read h0 slot RP (0/1), write h0 slot WP
#define L0BODY(T, RP, WP) do {                                                        \
        _Pragma("unroll")                                                             \
        for (int mt = 0; mt < 2; ++mt) {                                              \
            const f32x4 xv = *(const f32x4*)(xbF + (T) * Sv + me + mt * 16);          \
            const short8 a0 = *(const short8*)(Hhi + (RP) * HBUF + roA + mt * 16 * HSTR);      \
            const short8 a1 = *(const short8*)(Hhi + (RP) * HBUF + roA + mt * 16 * HSTR + 32); \
            f32x4 pre[4];                                                             \
            _Pragma("unroll")                                                         \
            for (int g = 0; g < 4; ++g) pre[g] = (f32x4){ba[g], ba[g], ba[g], ba[g]}; \
            _Pragma("unroll")                                                         \
            for (int g = 0; g < 4; ++g) pre[g] = MFMA16(a0, wreg[g],     pre[g]);     \
            _Pragma("unroll")                                                         \
            for (int g = 0; g < 4; ++g) pre[g] = MFMA16(a1, wreg[4 + g], pre[g]);     \
            float hv[4];                                                              \
            _Pragma("unroll")                                                         \
            for (int r = 0; r < 4; ++r) {                                             \
                const float xw = xv[r];                                               \
                hv[r] = cell1(pre[0][r] + xw * we[0], pre[1][r] + xw * we[1],         \
                              pre[2][r] + xw * we[2], pre[3][r] + xw * we[3],         \
                              cs[mt * 4 + r]);                                        \
            }                                                                         \
            const unsigned p01 = pkbf16(hv[0], hv[1]);                                \
            const unsigned p23 = pkbf16(hv[2], hv[3]);                                \
            Hhi[(WP) * HBUF + wiA + (mt * 16 + 0) * HSTR] = (short)p01;               \
            Hhi[(WP) * HBUF + wiA + (mt * 16 + 1) * HSTR] = (short)(p01 >> 16);       \
            Hhi[(WP) * HBUF + wiA + (mt * 16 + 2) * HSTR] = (short)p23;               \
            Hhi[(WP) * HBUF + wiA + (mt * 16 + 3) * HSTR] = (short)(p23 >> 16);       \
        }                                                                             \
    } while (0)

// layer-1 step: read h0 slot RP0 (0/1), h1 slot RPH (2/3), write h1 slot WPH
#define L1BODY(RP0, RPH, WPH) do {                                                    \
        _Pragma("unroll")                                                             \
        for (int mt = 0; mt < 2; ++mt) {                                              \
            const short8 b0 = *(const short8*)(Hhi + (RP0) * HBUF + roA + mt * 16 * HSTR);      \
            const short8 b1 = *(const short8*)(Hhi + (RP0) * HBUF + roA + mt * 16 * HSTR + 32); \
            const short8 d0 = *(const short8*)(Hhi + (RPH) * HBUF + roA + mt * 16 * HSTR);      \
            const short8 d1 = *(const short8*)(Hhi + (RPH) * HBUF + roA + mt * 16 * HSTR + 32); \
            f32x4 pre[4];                                                             \
            _Pragma("unroll")                                                         \
            for (int g = 0; g < 4; ++g) pre[g] = (f32x4){ba[g], ba[g], ba[g], ba[g]}; \
            _Pragma("unroll")                                                         \
            for (int g = 0; g < 4; ++g) pre[g] = MFMA16(b0, wreg[g],     pre[g]);     \
            _Pragma("unroll")                                                         \
            for (int g = 0; g < 4; ++g) pre[g] = MFMA16(b1, wreg[4 + g], pre[g]);     \
            _Pragma("unroll")                                                         \
            for (int g = 0; g < 4; ++g) {                                             \
                const short8 wf = *(const short8*)(Wlds + wb + g * WFR);              \
                pre[g] = MFMA16(d0, wf, pre[g]);                                      \
            }                                                                         \
            _Pragma("unroll")                                                         \
            for (int g = 0; g < 4; ++g) {                                             \
                const short8 wf = *(const short8*)(Wlds + wb + (4 + g) * WFR);        \
                pre[g] = MFMA16(d1, wf, pre[g]);                                      \
            }                                                                         \
            float hv[4];                                                              \
            _Pragma("unroll")                                                         \
            for (int r = 0; r < 4; ++r)                                               \
                hv[r] = cell1(pre[0][r], pre[1][r], pre[2][r], pre[3][r],             \
                              cs[mt * 4 + r]);                                        \
            const unsigned p01 = pkbf16(hv[0], hv[1]);                                \
            const unsigned p23 = pkbf16(hv[2], hv[3]);                                \
            Hhi[(WPH) * HBUF + wiA + (mt * 16 + 0) * HSTR] = (short)p01;              \
            Hhi[(WPH) * HBUF + wiA + (mt * 16 + 1) * HSTR] = (short)(p01 >> 16);      \
            Hhi[(WPH) * HBUF + wiA + (mt * 16 + 2) * HSTR] = (short)p23;              \
            Hhi[(WPH) * HBUF + wiA + (mt * 16 + 3) * HSTR] = (short)(p23 >> 16);      \
        }                                                                             \
    } while (0)

    // ---- encoder: 169 barrier intervals; interval k runs L0(k) || L1(k-1) ----
    // h0(t) -> slot t&1; h1(t) -> slot 2+(t&1). Slots 1,3 start zeroed (= t=-1).
    if (isL0) L0BODY(0, 1, 0);
    __syncthreads();
    for (int k = 1; k < 167; k += 2) {
        // odd interval k: L0(k): rd h0[0] wr h0[1]; L1(k-1): rd h0[0],h1[3] wr h1[2]
        if (isL0) L0BODY(k, 0, 1); else L1BODY(0, 3, 2);
        __syncthreads();
        // even interval k+1: L0: rd h0[1] wr h0[0]; L1(k): rd h0[1],h1[2] wr h1[3]
        if (isL0) L0BODY(k + 1, 1, 0); else L1BODY(1, 2, 3);
        __syncthreads();
    }
    if (isL0) L0BODY(167, 0, 1); else L1BODY(0, 3, 2);   // interval 167 (odd)
    __syncthreads();
    if (!isL0) L1BODY(1, 2, 3);                          // interval 168: L1(167) only
    __syncthreads();
    // h1(167) now in slot 3; c1 state lives in L1 waves' cs[8]

    // ================= decoder (runs on L1 waves; projection on all) =================
#pragma unroll
    for (int g = 0; g < 4; ++g) {
        const int j = g * 64 + uu;
        ba[g] = (bcih[j] + bchh[j]) * GF[g];
        we[g] = Wcih[j] * GF[g];
#pragma unroll
        for (int kc = 0; kc < 2; ++kc)
            hi8s(Wchh + j * 64 + kc * 32 + q * 8, GF[g], wreg[kc * 4 + g]);
    }
    if (tid < Mv) ybufF[tid] = xbF[(Lv - 1) * Sv + tid];
    __syncthreads();   // ybufF visible (h1 slot 3 already visible)

    const float boutF = bout[0];
    float* outp = out + b * HZv * Sv + s0;

#define DECBODY(T, RPH, WPH) do {                                                     \
        if (!isL0) {                                                                  \
            _Pragma("unroll")                                                         \
            for (int mt = 0; mt < 2; ++mt) {                                          \
                const f32x4 yv = *(const f32x4*)(ybufF + me + mt * 16);               \
                const short8 a0 = *(const short8*)(Hhi + (RPH) * HBUF + roA + mt * 16 * HSTR);      \
                const short8 a1 = *(const short8*)(Hhi + (RPH) * HBUF + roA + mt * 16 * HSTR + 32); \
                f32x4 pre[4];                                                         \
                _Pragma("unroll")                                                     \
                for (int g = 0; g < 4; ++g) pre[g] = (f32x4){ba[g], ba[g], ba[g], ba[g]}; \
                _Pragma("unroll")                                                     \
                for (int g = 0; g < 4; ++g) pre[g] = MFMA16(a0, wreg[g],     pre[g]); \
                _Pragma("unroll")                                                     \
                for (int g = 0; g < 4; ++g) pre[g] = MFMA16(a1, wreg[4 + g], pre[g]); \
                float hv[4];                                                          \
                _Pragma("unroll")                                                     \
                for (int r = 0; r < 4; ++r) {                                         \
                    const float xw = yv[r];                                           \
                    hv[r] = cell1(pre[0][r] + xw * we[0], pre[1][r] + xw * we[1],     \
                                  pre[2][r] + xw * we[2], pre[3][r] + xw * we[3],     \
                                  cs[mt * 4 + r]);                                    \
                }                                                                     \
                const unsigned p01 = pkbf16(hv[0], hv[1]);                            \
                const unsigned p23 = pkbf16(hv[2], hv[3]);                            \
                Hhi[(WPH) * HBUF + wiA + (mt * 16 + 0) * HSTR] = (short)p01;          \
                Hhi[(WPH) * HBUF + wiA + (mt * 16 + 1) * HSTR] = (short)(p01 >> 16);  \
                Hhi[(WPH) * HBUF + wiA + (mt * 16 + 2) * HSTR] = (short)p23;          \
                Hhi[(WPH) * HBUF + wiA + (mt * 16 + 3) * HSTR] = (short)(p23 >> 16);  \
            }                                                                         \
        }                                                                             \
        __syncthreads();   /* h(new) visible for y projection */                      \
        {                  /* all 1024 threads: 16 lanes per m, 4 k each */           \
            const int m  = tid >> 4;                                                  \
            const int pp = tid & 15;                                                  \
            float s = 0.f;                                                            \
            _Pragma("unroll")                                                         \
            for (int k2 = 0; k2 < 4; ++k2)                                            \
                s += b2f(Hhi[(WPH) * HBUF + m * HSTR + pp * 4 + k2]) * woutF[pp * 4 + k2]; \
            s += __shfl_xor(s, 1, 64);                                                \
            s += __shfl_xor(s, 2, 64);                                                \
            s += __shfl_xor(s, 4, 64);                                                \
            s += __shfl_xor(s, 8, 64);                                                \
            if (pp == 0) {                                                            \
                const float y = s + boutF;                                            \
                outp[(T) * Sv + m] = y;                                               \
                ybufF[m] = y;                                                         \
            }                                                                         \
        }                                                                             \
        __syncthreads();   /* ybufF visible for next step */                          \
    } while (0)

    for (int t = 0; t < HZv; t += 2) {
        DECBODY(t,     3, 2);
        DECBODY(t + 1, 2, 3);
    }
#undef DECBODY
#undef L1BODY
#undef L0BODY
}

extern "C" void kernel_launch(void* const* d_in, const int* in_sizes, int n_in,
                              void* d_out, int out_size, void* d_ws, size_t ws_size,
                              hipStream_t stream)
{
    const float* x_seq = (const float*)d_in[0];
    const float* Wih0  = (const float*)d_in[1];
    const float* Whh0  = (const float*)d_in[2];
    const float* bih0  = (const float*)d_in[3];
    const float* bhh0  = (const float*)d_in[4];
    const float* Wih1  = (const float*)d_in[5];
    const float* Whh1  = (const float*)d_in[6];
    const float* bih1  = (const float*)d_in[7];
    const float* bhh1  = (const float*)d_in[8];
    const float* Wcih  = (const float*)d_in[9];
    const float* Wchh  = (const float*)d_in[10];
    const float* bcih  = (const float*)d_in[11];
    const float* bchh  = (const float*)d_in[12];
    const float* Wout  = (const float*)d_in[13];
    const float* bout  = (const float*)d_in[14];
    float* out = (float*)d_out;

    hipLaunchKernelGGL(sitewise_lstm, dim3(Bv * (Sv / Mv)), dim3(1024), 0, stream,
                       x_seq, Wih0, Whh0, bih0, bhh0, Wih1, Whh1, bih1, bhh1,
                       Wcih, Wchh, bcih, bchh, Wout, bout, out);
}